// Round 9
// baseline (508.447 us; speedup 1.0000x reference)
//
#include <hip/hip_runtime.h>
#include <hip/hip_fp16.h>

// GDE func: out = MLP(relu(mean_agg(z,edges)@Wg + z@Ws + bg))
// Round 8 -> 9: revert to R5's winning structure (single-buffer drain,
// 48KB LDS, 3 blocks/CU) but raise per-wave arithmetic intensity:
// wave tile 128x64 (MI=8) -> 43.7 FLOP per LDS byte (MFMA-dominant) vs
// R5's 64x64 (32.8, LDS-bound). 4 waves/block for the 512-col layers.
// Keeps R6/R8-verified both-sides swizzle and R8's 32-lane gather.

typedef _Float16 f16;
typedef __attribute__((ext_vector_type(4))) _Float16 f16x4;
typedef __attribute__((ext_vector_type(8))) _Float16 f16x8;
typedef __attribute__((ext_vector_type(4))) float f32x4;

__device__ __forceinline__ void async_load16(const void* g, void* lds) {
  __builtin_amdgcn_global_load_lds(
      (const __attribute__((address_space(1))) void*)g,
      (__attribute__((address_space(3))) void*)lds, 16, 0, 0);
}

__device__ __forceinline__ float fast_tanh(float x) {
  float a = fabsf(x);
  float e = __expf(-2.0f * a);
  float r = (1.0f - e) * __builtin_amdgcn_rcpf(1.0f + e);
  return copysignf(r, x);
}

__global__ __launch_bounds__(256) void zero_kernel(int* __restrict__ p, int n) {
  int i = blockIdx.x * 256 + threadIdx.x;
  int stride = gridDim.x * 256;
  for (; i < n; i += stride) p[i] = 0;
}

// ---- CSR build ----
__global__ __launch_bounds__(256) void deg_count(const int* __restrict__ dst,
                                                 int* __restrict__ degi, int E) {
  int e = blockIdx.x * 256 + threadIdx.x;
  if (e < E) atomicAdd(&degi[dst[e]], 1);
}

__global__ __launch_bounds__(256) void scan_partial(const int* __restrict__ degi,
                                                    int* __restrict__ bsum, int N) {
  __shared__ int lds[256];
  int b = blockIdx.x, t = threadIdx.x;
  int s = 0;
#pragma unroll
  for (int j = 0; j < 4; ++j) {
    int idx = b * 1024 + t * 4 + j;
    if (idx < N) s += degi[idx];
  }
  lds[t] = s;
  __syncthreads();
  for (int off = 128; off > 0; off >>= 1) {
    if (t < off) lds[t] += lds[t + off];
    __syncthreads();
  }
  if (t == 0) bsum[b] = lds[0];
}

__global__ void scan_bsums(const int* __restrict__ bsum, int* __restrict__ boff,
                           int* __restrict__ row_start, int nb, int N) {
  if (threadIdx.x == 0 && blockIdx.x == 0) {
    int acc = 0;
    for (int i = 0; i < nb; ++i) { boff[i] = acc; acc += bsum[i]; }
    row_start[N] = acc;  // == E
  }
}

__global__ __launch_bounds__(256) void scan_final(
    const int* __restrict__ degi, const int* __restrict__ boff,
    int* __restrict__ row_start, int* __restrict__ cursor, int N) {
  __shared__ int lds[256];
  int b = blockIdx.x, t = threadIdx.x;
  int base = b * 1024;
  int v[4];
  int s = 0;
#pragma unroll
  for (int j = 0; j < 4; ++j) {
    int idx = base + t * 4 + j;
    v[j] = (idx < N) ? degi[idx] : 0;
    s += v[j];
  }
  lds[t] = s;
  __syncthreads();
  for (int off = 1; off < 256; off <<= 1) {
    int x = lds[t];
    int y = (t >= off) ? lds[t - off] : 0;
    __syncthreads();
    lds[t] = x + y;
    __syncthreads();
  }
  int pre = boff[b] + lds[t] - s;
#pragma unroll
  for (int j = 0; j < 4; ++j) {
    int idx = base + t * 4 + j;
    if (idx < N) { row_start[idx] = pre; cursor[idx] = pre; pre += v[j]; }
  }
}

__global__ __launch_bounds__(256) void fill_adj(const int* __restrict__ src,
                                                const int* __restrict__ dst,
                                                int* __restrict__ cursor,
                                                int* __restrict__ adj, int E) {
  int e = blockIdx.x * 256 + threadIdx.x;
  if (e >= E) return;
  int p = atomicAdd(&cursor[dst[e]], 1);
  adj[p] = src[e];
}

// ---- fused gather + mean + Xcat: 32 lanes per node (2 nodes/wave) ----
__global__ __launch_bounds__(256) void gather_xcat(
    const float* __restrict__ z, const int* __restrict__ row_start,
    const int* __restrict__ adj, f16* __restrict__ Xc, int N) {
  int node = (blockIdx.x * 256 + threadIdx.x) >> 5;
  if (node >= N) return;
  int lane = threadIdx.x & 31;
  int beg = row_start[node], end = row_start[node + 1];
  float4 s0 = {0, 0, 0, 0}, s1 = {0, 0, 0, 0}, s2 = {0, 0, 0, 0}, s3 = {0, 0, 0, 0};
  int i = beg;
  for (; i + 4 <= end; i += 4) {
    int n0 = adj[i], n1 = adj[i + 1], n2 = adj[i + 2], n3 = adj[i + 3];
    float4 v0 = *(const float4*)(z + (long long)n0 * 128 + 4 * lane);
    float4 v1 = *(const float4*)(z + (long long)n1 * 128 + 4 * lane);
    float4 v2 = *(const float4*)(z + (long long)n2 * 128 + 4 * lane);
    float4 v3 = *(const float4*)(z + (long long)n3 * 128 + 4 * lane);
    s0.x += v0.x; s0.y += v0.y; s0.z += v0.z; s0.w += v0.w;
    s1.x += v1.x; s1.y += v1.y; s1.z += v1.z; s1.w += v1.w;
    s2.x += v2.x; s2.y += v2.y; s2.z += v2.z; s2.w += v2.w;
    s3.x += v3.x; s3.y += v3.y; s3.z += v3.z; s3.w += v3.w;
  }
  for (; i < end; ++i) {
    float4 v = *(const float4*)(z + (long long)adj[i] * 128 + 4 * lane);
    s0.x += v.x; s0.y += v.y; s0.z += v.z; s0.w += v.w;
  }
  s0.x += s1.x + s2.x + s3.x;
  s0.y += s1.y + s2.y + s3.y;
  s0.z += s1.z + s2.z + s3.z;
  s0.w += s1.w + s2.w + s3.w;
  int dg = end - beg;
  float inv = 1.0f / (float)(dg > 1 ? dg : 1);
  long long o = (long long)node * 256;
  f16x4 m;
  m[0] = (f16)(s0.x * inv); m[1] = (f16)(s0.y * inv);
  m[2] = (f16)(s0.z * inv); m[3] = (f16)(s0.w * inv);
  *(f16x4*)(Xc + o + 4 * lane) = m;
  float4 zv = *(const float4*)(z + (long long)node * 128 + 4 * lane);
  f16x4 zc;
  zc[0] = (f16)zv.x; zc[1] = (f16)zv.y; zc[2] = (f16)zv.z; zc[3] = (f16)zv.w;
  *(f16x4*)(Xc + o + 128 + 4 * lane) = zc;
}

// ---- weight prep (Wt stored [col][K] row-major f16) ----
__global__ __launch_bounds__(256) void build_wgs(
    const float* __restrict__ Wg, const float* __restrict__ Ws, f16* __restrict__ Wt) {
  int i = blockIdx.x * 256 + threadIdx.x;
  if (i >= 128 * 256) return;
  int n = i >> 8, k = i & 255;
  float v = (k < 128) ? Wg[k * 128 + n] : Ws[(k - 128) * 128 + n];
  Wt[i] = (f16)v;
}

__global__ __launch_bounds__(256) void transpose_cast(
    const float* __restrict__ W, f16* __restrict__ Wt, int K, int N) {
  int i = blockIdx.x * 256 + threadIdx.x;
  if (i >= K * N) return;
  int n = i / K, k = i - n * K;
  Wt[i] = (f16)W[k * N + n];
}

// --------- single-buffer drain MFMA GEMM (R5 schedule, taller wave) ---------
// C[M,NOUT] = act(X[M,K] @ Wt^T + bias); Wt is [NOUT][K] f16, BK=64.
// Wave grid WM x WN, wave tile (MI*16) x 64 (NJ=4). BM = WM*MI*16 = 128.
//   512-col layers: WM=1 WN=4 MI=8 -> 4 waves, wave 128x64, BN=256, 48KB LDS
//   128-col layers: WM=2 WN=2 MI=4 -> 4 waves, wave  64x64, BN=128, 32KB LDS
// Schedule per K-step: STAGE -> __syncthreads -> COMPUTE -> __syncthreads
// (R5-proven; cross-block overlap at 3 blocks/CU hides the drain).
// Both-sides swizzle (R6/R8-verified): source slot ^= row&7, read XORs same.
template <int K, int NOUT, int WM, int WN, int MI, int ACT, bool OUTF32>
__global__ __launch_bounds__(WM * WN * 64) void gemm_r(
    const f16* __restrict__ X, const f16* __restrict__ Wt,
    const float* __restrict__ bias, void* __restrict__ OutV, int M) {
  constexpr int NJ = 4;
  constexpr int BM = WM * MI * 16;   // 128 in all instantiations
  constexpr int BN = WN * NJ * 16;
  constexpr int NTHR = WM * WN * 64;
  constexpr int CA = (BM * 128) / (NTHR * 16);
  constexpr int CB = (BN * 128) / (NTHR * 16);
  __shared__ __align__(16) f16 As[BM * 64];
  __shared__ __align__(16) f16 Bs[BN * 64];

  const int tid = threadIdx.x;
  const int wid = tid >> 6, lane = tid & 63;
  const int wm = wid / WN, wn = wid % WN;
  const int lr = lane & 15, lq = lane >> 4;
  const int rxor = lr & 7;
  const long long m0 = (long long)blockIdx.x * BM;
  const int n0 = blockIdx.y * BN;

  const f16* Ag = X + m0 * K;
  const f16* Bg = Wt + (long long)n0 * K;

  // hoisted per-thread stage source offsets (swizzled slot)
  long long aOff[CA], bOff[CB];
#pragma unroll
  for (int c = 0; c < CA; ++c) {
    int f = c * NTHR + tid;
    int row = f >> 3, ss = (f & 7) ^ (row & 7);
    aOff[c] = (long long)row * K + ss * 8;
  }
#pragma unroll
  for (int c = 0; c < CB; ++c) {
    int f = c * NTHR + tid;
    int row = f >> 3, ss = (f & 7) ^ (row & 7);
    bOff[c] = (long long)row * K + ss * 8;
  }

  f32x4 acc[MI][NJ];
#pragma unroll
  for (int i = 0; i < MI; ++i)
#pragma unroll
    for (int j = 0; j < NJ; ++j)
#pragma unroll
      for (int r = 0; r < 4; ++r) acc[i][j][r] = 0.0f;

#pragma unroll 1
  for (int k0 = 0; k0 < K; k0 += 64) {
#pragma unroll
    for (int c = 0; c < CA; ++c)
      async_load16(Ag + aOff[c] + k0, (char*)As + c * NTHR * 16 + wid * 1024);
#pragma unroll
    for (int c = 0; c < CB; ++c)
      async_load16(Bg + bOff[c] + k0, (char*)Bs + c * NTHR * 16 + wid * 1024);
    __syncthreads();
#pragma unroll
    for (int kk = 0; kk < 64; kk += 32) {
      const int co = (((kk >> 3) + lq) ^ rxor) * 16;  // swizzled byte col
      f16x8 a[MI], b[NJ];
#pragma unroll
      for (int i = 0; i < MI; ++i)
        a[i] = *reinterpret_cast<const f16x8*>(
            (const char*)As + (wm * MI * 16 + i * 16 + lr) * 128 + co);
#pragma unroll
      for (int j = 0; j < NJ; ++j)
        b[j] = *reinterpret_cast<const f16x8*>(
            (const char*)Bs + (wn * NJ * 16 + j * 16 + lr) * 128 + co);
#pragma unroll
      for (int i = 0; i < MI; ++i)
#pragma unroll
        for (int j = 0; j < NJ; ++j)
          acc[i][j] = __builtin_amdgcn_mfma_f32_16x16x32_f16(a[i], b[j], acc[i][j], 0, 0, 0);
    }
    __syncthreads();
  }

#pragma unroll
  for (int i = 0; i < MI; ++i) {
#pragma unroll
    for (int j = 0; j < NJ; ++j) {
      int col = n0 + wn * NJ * 16 + j * 16 + lr;
      float bv = bias[col];
#pragma unroll
      for (int r = 0; r < 4; ++r) {
        long long row = m0 + wm * MI * 16 + i * 16 + lq * 4 + r;
        if (row < M) {
          float v = acc[i][j][r] + bv;
          if (ACT == 1) v = fmaxf(v, 0.0f);
          else if (ACT == 2) v = fast_tanh(v);
          if constexpr (OUTF32)
            ((float*)OutV)[row * NOUT + col] = v;
          else
            ((f16*)OutV)[row * NOUT + col] = (f16)v;
        }
      }
    }
  }
}

extern "C" void kernel_launch(void* const* d_in, const int* in_sizes, int n_in,
                              void* d_out, int out_size, void* d_ws, size_t ws_size,
                              hipStream_t stream) {
  const float* z  = (const float*)d_in[0];
  const int*   ei = (const int*)d_in[1];
  const float* Wg = (const float*)d_in[2];
  const float* Ws = (const float*)d_in[3];
  const float* bg = (const float*)d_in[4];
  const float* W1 = (const float*)d_in[5];
  const float* b1 = (const float*)d_in[6];
  const float* W2 = (const float*)d_in[7];
  const float* b2 = (const float*)d_in[8];
  const float* W3 = (const float*)d_in[9];
  const float* b3 = (const float*)d_in[10];

  const int Nn = in_sizes[0] / 128;
  const int E  = in_sizes[1] / 2;
  const int* src = ei;
  const int* dst = ei + E;
  const int nb = (Nn + 1023) / 1024;
  const int gm = (Nn + 255) / 256;
  const long long Mpad = (long long)gm * 256;
  const int gm128 = (int)(Mpad / 128);   // all GEMMs use BM=128

  // workspace overlay (peak ~207 MB):
  //   [0, 51.2M)        Xc   (gather -> gemm1)
  //   [51.2, 76.8M)     h1   (gemm1 -> gemm2)
  //   [76.8, ~80.5M)    CSR  (build -> gather)
  //   [0, 102.4M)       h3   (gemm3 -> gemm4; overlays Xc,h1,CSR - all dead)
  //   [102.4, 204.8M)   h2   (gemm2 -> gemm3)
  //   [204.8M, ...)     prepped weights (~1.7 MB)
  char* base = (char*)d_ws;
  const size_t XCB  = (size_t)Mpad * 256 * 2;
  const size_t H1B  = (size_t)Mpad * 128 * 2;
  const size_t H3B  = (size_t)Mpad * 512 * 2;
  f16* Xc = (f16*)(base);
  f16* h1 = (f16*)(base + XCB);
  f16* h3 = (f16*)(base);
  size_t off = XCB + H1B;
  auto alloc = [&](size_t b) -> void* {
    void* p = base + off;
    off += (b + 255) & ~(size_t)255;
    return p;
  };
  int* degi      = (int*)alloc((size_t)Nn * 4);
  int* row_start = (int*)alloc((size_t)(Nn + 1) * 4);
  int* cursor    = (int*)alloc((size_t)Nn * 4);
  int* adj       = (int*)alloc((size_t)E * 4);
  int* bsum      = (int*)alloc((size_t)nb * 4);
  int* boff      = (int*)alloc((size_t)nb * 4);
  off = H3B;  // h2 starts after h3 span
  f16* h2  = (f16*)alloc((size_t)Mpad * 512 * 2);
  f16* wgs = (f16*)alloc((size_t)128 * 256 * 2);
  f16* wt1 = (f16*)alloc((size_t)512 * 128 * 2);
  f16* wt2 = (f16*)alloc((size_t)512 * 512 * 2);
  f16* wt3 = (f16*)alloc((size_t)128 * 512 * 2);

  // CSR build
  zero_kernel<<<(Nn + 255) / 256, 256, 0, stream>>>(degi, Nn);
  deg_count<<<(E + 255) / 256, 256, 0, stream>>>(dst, degi, E);
  scan_partial<<<nb, 256, 0, stream>>>(degi, bsum, Nn);
  scan_bsums<<<1, 64, 0, stream>>>(bsum, boff, row_start, nb, Nn);
  scan_final<<<nb, 256, 0, stream>>>(degi, boff, row_start, cursor, Nn);
  fill_adj<<<(E + 255) / 256, 256, 0, stream>>>(src, dst, cursor, adj, E);

  // weight prep
  build_wgs<<<(128 * 256 + 255) / 256, 256, 0, stream>>>(Wg, Ws, wgs);
  transpose_cast<<<(128 * 512 + 255) / 256, 256, 0, stream>>>(W1, wt1, 128, 512);
  transpose_cast<<<(512 * 512 + 255) / 256, 256, 0, stream>>>(W2, wt2, 512, 512);
  transpose_cast<<<(512 * 128 + 255) / 256, 256, 0, stream>>>(W3, wt3, 512, 128);

  // gather + Xcat (32 lanes per node)
  {
    long long tot = (long long)Nn * 32;
    gather_xcat<<<(int)((tot + 255) / 256), 256, 0, stream>>>(z, row_start, adj, Xc, Nn);
  }

  // L1 (K=256,N=128): 64x64 waves; L2/L3 (N=512): 128x64 waves; L4: 64x64.
  gemm_r<256, 128, 2, 2, 4, 1, false><<<dim3(gm128, 1), 256, 0, stream>>>(Xc, wgs, bg, (void*)h1, Nn);
  gemm_r<128, 512, 1, 4, 8, 2, false><<<dim3(gm128, 2), 256, 0, stream>>>(h1, wt1, b1, (void*)h2, Nn);
  gemm_r<512, 512, 1, 4, 8, 2, false><<<dim3(gm128, 2), 256, 0, stream>>>(h2, wt2, b2, (void*)h3, Nn);
  gemm_r<512, 128, 2, 2, 4, 0, true><<<dim3(gm128, 1), 256, 0, stream>>>(h3, wt3, b3, d_out, Nn);
}

// Round 10
// 414.572 us; speedup vs baseline: 1.2264x; 1.2264x over previous
//
#include <hip/hip_runtime.h>
#include <hip/hip_fp16.h>

// GDE func: out = MLP(relu(mean_agg(z,edges)@Wg + z@Ws + bg))
// Round 9 -> 10: keep the PROVEN R5 GEMM core (BM=128, BN=256, 8 waves of
// 64x64, 48KB LDS, drain schedule, both-sides swizzle) but fuse layer
// boundaries to kill h1/h3 HBM round-trips and two kernels:
//   fused12: L1 -> h1 in LDS -> L2 -> h2          (h1 never in HBM)
//   fused34: L3 (R5 core) -> h3 quarters in LDS -> L4 partial -> atomicAdd out
// out pre-filled with b3; 11 dispatches total (was 15).

typedef _Float16 f16;
typedef __attribute__((ext_vector_type(4))) _Float16 f16x4;
typedef __attribute__((ext_vector_type(8))) _Float16 f16x8;
typedef __attribute__((ext_vector_type(4))) float f32x4;

__device__ __forceinline__ void async_load16(const void* g, void* lds) {
  __builtin_amdgcn_global_load_lds(
      (const __attribute__((address_space(1))) void*)g,
      (__attribute__((address_space(3))) void*)lds, 16, 0, 0);
}

__device__ __forceinline__ float fast_tanh(float x) {
  float a = fabsf(x);
  float e = __expf(-2.0f * a);
  float r = (1.0f - e) * __builtin_amdgcn_rcpf(1.0f + e);
  return copysignf(r, x);
}

__global__ __launch_bounds__(256) void zero_kernel(int* __restrict__ p, int n) {
  int i = blockIdx.x * 256 + threadIdx.x;
  int stride = gridDim.x * 256;
  for (; i < n; i += stride) p[i] = 0;
}

// ---- CSR build ----
__global__ __launch_bounds__(256) void deg_count(const int* __restrict__ dst,
                                                 int* __restrict__ degi, int E) {
  int e = blockIdx.x * 256 + threadIdx.x;
  if (e < E) atomicAdd(&degi[dst[e]], 1);
}

__global__ __launch_bounds__(256) void scan_partial(const int* __restrict__ degi,
                                                    int* __restrict__ bsum, int N) {
  __shared__ int lds[256];
  int b = blockIdx.x, t = threadIdx.x;
  int s = 0;
#pragma unroll
  for (int j = 0; j < 4; ++j) {
    int idx = b * 1024 + t * 4 + j;
    if (idx < N) s += degi[idx];
  }
  lds[t] = s;
  __syncthreads();
  for (int off = 128; off > 0; off >>= 1) {
    if (t < off) lds[t] += lds[t + off];
    __syncthreads();
  }
  if (t == 0) bsum[b] = lds[0];
}

__global__ void scan_bsums(const int* __restrict__ bsum, int* __restrict__ boff,
                           int* __restrict__ row_start, int nb, int N) {
  if (threadIdx.x == 0 && blockIdx.x == 0) {
    int acc = 0;
    for (int i = 0; i < nb; ++i) { boff[i] = acc; acc += bsum[i]; }
    row_start[N] = acc;  // == E
  }
}

__global__ __launch_bounds__(256) void scan_final(
    const int* __restrict__ degi, const int* __restrict__ boff,
    int* __restrict__ row_start, int* __restrict__ cursor, int N) {
  __shared__ int lds[256];
  int b = blockIdx.x, t = threadIdx.x;
  int base = b * 1024;
  int v[4];
  int s = 0;
#pragma unroll
  for (int j = 0; j < 4; ++j) {
    int idx = base + t * 4 + j;
    v[j] = (idx < N) ? degi[idx] : 0;
    s += v[j];
  }
  lds[t] = s;
  __syncthreads();
  for (int off = 1; off < 256; off <<= 1) {
    int x = lds[t];
    int y = (t >= off) ? lds[t - off] : 0;
    __syncthreads();
    lds[t] = x + y;
    __syncthreads();
  }
  int pre = boff[b] + lds[t] - s;
#pragma unroll
  for (int j = 0; j < 4; ++j) {
    int idx = base + t * 4 + j;
    if (idx < N) { row_start[idx] = pre; cursor[idx] = pre; pre += v[j]; }
  }
}

__global__ __launch_bounds__(256) void fill_adj(const int* __restrict__ src,
                                                const int* __restrict__ dst,
                                                int* __restrict__ cursor,
                                                int* __restrict__ adj, int E) {
  int e = blockIdx.x * 256 + threadIdx.x;
  if (e >= E) return;
  int p = atomicAdd(&cursor[dst[e]], 1);
  adj[p] = src[e];
}

// ---- fused gather + mean + Xcat: 32 lanes per node (2 nodes/wave) ----
__global__ __launch_bounds__(256) void gather_xcat(
    const float* __restrict__ z, const int* __restrict__ row_start,
    const int* __restrict__ adj, f16* __restrict__ Xc, int N) {
  int node = (blockIdx.x * 256 + threadIdx.x) >> 5;
  if (node >= N) return;
  int lane = threadIdx.x & 31;
  int beg = row_start[node], end = row_start[node + 1];
  float4 s0 = {0, 0, 0, 0}, s1 = {0, 0, 0, 0}, s2 = {0, 0, 0, 0}, s3 = {0, 0, 0, 0};
  int i = beg;
  for (; i + 4 <= end; i += 4) {
    int n0 = adj[i], n1 = adj[i + 1], n2 = adj[i + 2], n3 = adj[i + 3];
    float4 v0 = *(const float4*)(z + (long long)n0 * 128 + 4 * lane);
    float4 v1 = *(const float4*)(z + (long long)n1 * 128 + 4 * lane);
    float4 v2 = *(const float4*)(z + (long long)n2 * 128 + 4 * lane);
    float4 v3 = *(const float4*)(z + (long long)n3 * 128 + 4 * lane);
    s0.x += v0.x; s0.y += v0.y; s0.z += v0.z; s0.w += v0.w;
    s1.x += v1.x; s1.y += v1.y; s1.z += v1.z; s1.w += v1.w;
    s2.x += v2.x; s2.y += v2.y; s2.z += v2.z; s2.w += v2.w;
    s3.x += v3.x; s3.y += v3.y; s3.z += v3.z; s3.w += v3.w;
  }
  for (; i < end; ++i) {
    float4 v = *(const float4*)(z + (long long)adj[i] * 128 + 4 * lane);
    s0.x += v.x; s0.y += v.y; s0.z += v.z; s0.w += v.w;
  }
  s0.x += s1.x + s2.x + s3.x;
  s0.y += s1.y + s2.y + s3.y;
  s0.z += s1.z + s2.z + s3.z;
  s0.w += s1.w + s2.w + s3.w;
  int dg = end - beg;
  float inv = 1.0f / (float)(dg > 1 ? dg : 1);
  long long o = (long long)node * 256;
  f16x4 m;
  m[0] = (f16)(s0.x * inv); m[1] = (f16)(s0.y * inv);
  m[2] = (f16)(s0.z * inv); m[3] = (f16)(s0.w * inv);
  *(f16x4*)(Xc + o + 4 * lane) = m;
  float4 zv = *(const float4*)(z + (long long)node * 128 + 4 * lane);
  f16x4 zc;
  zc[0] = (f16)zv.x; zc[1] = (f16)zv.y; zc[2] = (f16)zv.z; zc[3] = (f16)zv.w;
  *(f16x4*)(Xc + o + 128 + 4 * lane) = zc;
}

// ---- merged weight prep: wgs[128c][256k], wt1[512c][128k], wt2[512c][512k],
// wt3[128c][512k], all f16 [col][K] ----
__global__ __launch_bounds__(256) void prep_weights(
    const float* __restrict__ Wg, const float* __restrict__ Ws,
    const float* __restrict__ W1, const float* __restrict__ W2,
    const float* __restrict__ W3, f16* __restrict__ wgs, f16* __restrict__ wt1,
    f16* __restrict__ wt2, f16* __restrict__ wt3) {
  int i = blockIdx.x * 256 + threadIdx.x;
  int stride = gridDim.x * 256;
  for (; i < 425984; i += stride) {
    if (i < 32768) {
      int n = i >> 8, k = i & 255;
      wgs[i] = (f16)((k < 128) ? Wg[k * 128 + n] : Ws[(k - 128) * 128 + n]);
    } else if (i < 98304) {
      int j = i - 32768, c = j >> 7, k = j & 127;
      wt1[j] = (f16)W1[k * 512 + c];
    } else if (i < 360448) {
      int j = i - 98304, c = j >> 9, k = j & 511;
      wt2[j] = (f16)W2[k * 512 + c];
    } else {
      int j = i - 360448, c = j >> 9, k = j & 511;
      wt3[j] = (f16)W3[k * 128 + c];
    }
  }
}

// ---- pre-fill out with b3 (L4 partials atomicAdd on top) ----
__global__ __launch_bounds__(256) void fill_out(float* __restrict__ out,
                                                const float* __restrict__ b3, int n) {
  int i = blockIdx.x * 256 + threadIdx.x;
  int stride = gridDim.x * 256;
  for (; i < n; i += stride) out[i] = b3[i & 127];
}

// ======================= fused L1+L2 =======================
// h2[128p,512] = tanh( relu(Xc@wgs^T + bg) @ wt1^T + b1 ), per 128-row panel.
// 4 waves (2x2, 64x64). LDS 48KB: phase1 As[0,16K) Bs[16K,32K);
// H1(relu'd, swizzled) [0,32K); W1 slice [32K,48K).
__global__ __launch_bounds__(256) void fused12(
    const f16* __restrict__ Xc, const f16* __restrict__ wgs,
    const f16* __restrict__ wt1, const float* __restrict__ bg,
    const float* __restrict__ b1, f16* __restrict__ h2) {
  __shared__ __align__(16) char L[49152];
  const int tid = threadIdx.x;
  const int wid = tid >> 6, lane = tid & 63;
  const int wm = wid & 1, wn = wid >> 1;  // 2x2
  const int lr = lane & 15, lq = lane >> 4;
  const int key = lr & 7;
  const long long m0 = (long long)blockIdx.x * 128;
  const f16* Ag = Xc + m0 * 256;

  f32x4 acc[4][4];
#pragma unroll
  for (int i = 0; i < 4; ++i)
#pragma unroll
    for (int j = 0; j < 4; ++j)
#pragma unroll
      for (int r = 0; r < 4; ++r) acc[i][j][r] = 0.0f;

  // ---- phase 1: L1, K=256 ----
#pragma unroll 1
  for (int k0 = 0; k0 < 256; k0 += 64) {
#pragma unroll
    for (int c = 0; c < 4; ++c) {
      int f = c * 256 + tid;
      int row = f >> 3, ss = (f & 7) ^ (row & 7);
      async_load16(Ag + (long long)row * 256 + k0 + ss * 8, L + f * 16);
    }
#pragma unroll
    for (int c = 0; c < 4; ++c) {
      int f = c * 256 + tid;
      int row = f >> 3, ss = (f & 7) ^ (row & 7);
      async_load16(wgs + row * 256 + k0 + ss * 8, L + 16384 + f * 16);
    }
    __syncthreads();
#pragma unroll
    for (int kk = 0; kk < 64; kk += 32) {
      const int co = (((kk >> 3) + lq) ^ key) * 16;
      f16x8 a[4], b[4];
#pragma unroll
      for (int i = 0; i < 4; ++i)
        a[i] = *reinterpret_cast<const f16x8*>(L + (wm * 64 + i * 16 + lr) * 128 + co);
#pragma unroll
      for (int j = 0; j < 4; ++j)
        b[j] = *reinterpret_cast<const f16x8*>(L + 16384 + (wn * 64 + j * 16 + lr) * 128 + co);
#pragma unroll
      for (int i = 0; i < 4; ++i)
#pragma unroll
        for (int j = 0; j < 4; ++j)
          acc[i][j] = __builtin_amdgcn_mfma_f32_16x16x32_f16(a[i], b[j], acc[i][j], 0, 0, 0);
    }
    __syncthreads();
  }

  // acc -> H1 (relu + bg), swizzled [128][128] f16 at L[0,32K)
#pragma unroll
  for (int i = 0; i < 4; ++i)
#pragma unroll
    for (int j = 0; j < 4; ++j) {
      int col = wn * 64 + j * 16 + lr;
      float bv = bg[col];
#pragma unroll
      for (int r = 0; r < 4; ++r) {
        int row = wm * 64 + i * 16 + lq * 4 + r;
        float v = fmaxf(acc[i][j][r] + bv, 0.0f);
        *reinterpret_cast<f16*>(L + row * 256 + (((col >> 3) ^ (row & 7)) * 16) +
                                (col & 7) * 2) = (f16)v;
      }
    }
  __syncthreads();

  // ---- phase 2: L2, K=128 (from H1), per 128-col block ----
#pragma unroll 1
  for (int cb = 0; cb < 4; ++cb) {
#pragma unroll
    for (int i = 0; i < 4; ++i)
#pragma unroll
      for (int j = 0; j < 4; ++j)
#pragma unroll
        for (int r = 0; r < 4; ++r) acc[i][j][r] = 0.0f;

#pragma unroll 1
    for (int kc = 0; kc < 2; ++kc) {
      // stage wt1 slice: rows cb*128..+127, k window kc*64 -> [32K,48K)
#pragma unroll
      for (int c = 0; c < 4; ++c) {
        int f = c * 256 + tid;
        int row = f >> 3, ss = (f & 7) ^ (row & 7);
        async_load16(wt1 + (long long)(cb * 128 + row) * 128 + kc * 64 + ss * 8,
                     L + 32768 + f * 16);
      }
      __syncthreads();
#pragma unroll
      for (int kk = 0; kk < 64; kk += 32) {
        const int aslot = kc * 8 + (kk >> 3) + lq;     // H1 slot 0..15
        const int bco = (((kk >> 3) + lq) ^ key) * 16; // W1sl byte col
        f16x8 a[4], b[4];
#pragma unroll
        for (int i = 0; i < 4; ++i)
          a[i] = *reinterpret_cast<const f16x8*>(
              L + (wm * 64 + i * 16 + lr) * 256 + (aslot ^ key) * 16);
#pragma unroll
        for (int j = 0; j < 4; ++j)
          b[j] = *reinterpret_cast<const f16x8*>(
              L + 32768 + (wn * 64 + j * 16 + lr) * 128 + bco);
#pragma unroll
        for (int i = 0; i < 4; ++i)
#pragma unroll
          for (int j = 0; j < 4; ++j)
            acc[i][j] = __builtin_amdgcn_mfma_f32_16x16x32_f16(a[i], b[j], acc[i][j], 0, 0, 0);
      }
      __syncthreads();
    }
    // epilogue: tanh -> h2 cols cb*128..
#pragma unroll
    for (int i = 0; i < 4; ++i)
#pragma unroll
      for (int j = 0; j < 4; ++j) {
        int colg = cb * 128 + wn * 64 + j * 16 + lr;
        float bv = b1[colg];
#pragma unroll
        for (int r = 0; r < 4; ++r) {
          long long row = m0 + wm * 64 + i * 16 + lq * 4 + r;
          h2[row * 512 + colg] = (f16)fast_tanh(acc[i][j][r] + bv);
        }
      }
  }
}

// ======================= fused L3+L4 =======================
// h3 = tanh(h2@wt2^T + b2) computed per (panel, y-half); h3 64-col quarters
// round-trip through LDS; L4 partials accumulate in regs; atomicAdd to out
// (pre-filled with b3). Phase A core = R5 gemm (8 waves 2x4, 64x64, 48KB).
__global__ __launch_bounds__(512) void fused34(
    const f16* __restrict__ h2, const f16* __restrict__ wt2,
    const f16* __restrict__ wt3, const float* __restrict__ b2,
    float* __restrict__ out, int M) {
  __shared__ __align__(16) char L[49152];
  const int tid = threadIdx.x;
  const int wid = tid >> 6, lane = tid & 63;
  const int wm = wid & 1, wn = wid >> 1;  // 2x4
  const int lr = lane & 15, lq = lane >> 4;
  const int key = lr & 7;
  const long long m0 = (long long)blockIdx.x * 128;
  const int n0 = blockIdx.y * 256;
  const f16* Ag = h2 + m0 * 512;
  const f16* Bg = wt2 + (long long)n0 * 512;

  f32x4 acc[4][4];
#pragma unroll
  for (int i = 0; i < 4; ++i)
#pragma unroll
    for (int j = 0; j < 4; ++j)
#pragma unroll
      for (int r = 0; r < 4; ++r) acc[i][j][r] = 0.0f;

  // ---- phase A: L3 (K=512), R5 core ----
#pragma unroll 1
  for (int k0 = 0; k0 < 512; k0 += 64) {
#pragma unroll
    for (int c = 0; c < 2; ++c) {
      int f = c * 512 + tid;
      int row = f >> 3, ss = (f & 7) ^ (row & 7);
      async_load16(Ag + (long long)row * 512 + k0 + ss * 8, L + f * 16);
    }
#pragma unroll
    for (int c = 0; c < 4; ++c) {
      int f = c * 512 + tid;
      int row = f >> 3, ss = (f & 7) ^ (row & 7);
      async_load16(Bg + (long long)row * 512 + k0 + ss * 8, L + 16384 + f * 16);
    }
    __syncthreads();
#pragma unroll
    for (int kk = 0; kk < 64; kk += 32) {
      const int co = (((kk >> 3) + lq) ^ key) * 16;
      f16x8 a[4], b[4];
#pragma unroll
      for (int i = 0; i < 4; ++i)
        a[i] = *reinterpret_cast<const f16x8*>(L + (wm * 64 + i * 16 + lr) * 128 + co);
#pragma unroll
      for (int j = 0; j < 4; ++j)
        b[j] = *reinterpret_cast<const f16x8*>(L + 16384 + (wn * 64 + j * 16 + lr) * 128 + co);
#pragma unroll
      for (int i = 0; i < 4; ++i)
#pragma unroll
        for (int j = 0; j < 4; ++j)
          acc[i][j] = __builtin_amdgcn_mfma_f32_16x16x32_f16(a[i], b[j], acc[i][j], 0, 0, 0);
    }
    __syncthreads();
  }

  // ---- phase B: per 64-col quarter q: tanh->H3q (LDS) + wt3 slice -> L4 ----
  f32x4 oacc[4][2];
#pragma unroll
  for (int i = 0; i < 4; ++i)
#pragma unroll
    for (int j = 0; j < 2; ++j)
#pragma unroll
      for (int r = 0; r < 4; ++r) oacc[i][j][r] = 0.0f;

#pragma unroll 1
  for (int q = 0; q < 4; ++q) {
    if (wn == q) {  // owning waves write their 64-col stripe as h3 (f16)
#pragma unroll
      for (int i = 0; i < 4; ++i)
#pragma unroll
        for (int j = 0; j < 4; ++j) {
          int col = j * 16 + lr;  // 0..63 within quarter
          float bv = b2[n0 + q * 64 + col];
#pragma unroll
          for (int r = 0; r < 4; ++r) {
            int row = wm * 64 + i * 16 + lq * 4 + r;
            *reinterpret_cast<f16*>(L + row * 128 + (((col >> 3) ^ (row & 7)) * 16) +
                                    (col & 7) * 2) = (f16)fast_tanh(acc[i][j][r] + bv);
          }
        }
    }
    // stage wt3 slice: all 128 out-cols, k window n0+q*64 -> [16K,32K)
#pragma unroll
    for (int c = 0; c < 2; ++c) {
      int f = c * 512 + tid;
      int row = f >> 3, ss = (f & 7) ^ (row & 7);
      async_load16(wt3 + (long long)row * 512 + n0 + q * 64 + ss * 8,
                   L + 16384 + f * 16);
    }
    __syncthreads();
    // L4 partial: wave tile 64 rows x 32 cols (2x4 grid)
#pragma unroll
    for (int kk = 0; kk < 64; kk += 32) {
      const int co = (((kk >> 3) + lq) ^ key) * 16;
      f16x8 a[4], b[2];
#pragma unroll
      for (int i = 0; i < 4; ++i)
        a[i] = *reinterpret_cast<const f16x8*>(L + (wm * 64 + i * 16 + lr) * 128 + co);
#pragma unroll
      for (int j = 0; j < 2; ++j)
        b[j] = *reinterpret_cast<const f16x8*>(
            L + 16384 + (wn * 32 + j * 16 + lr) * 128 + co);
#pragma unroll
      for (int i = 0; i < 4; ++i)
#pragma unroll
        for (int j = 0; j < 2; ++j)
          oacc[i][j] = __builtin_amdgcn_mfma_f32_16x16x32_f16(a[i], b[j], oacc[i][j], 0, 0, 0);
    }
    __syncthreads();
  }

  // ---- atomic merge (y=0 and y=1 blocks both add; out pre-filled b3) ----
#pragma unroll
  for (int i = 0; i < 4; ++i)
#pragma unroll
    for (int j = 0; j < 2; ++j) {
      int col = wn * 32 + j * 16 + lr;
#pragma unroll
      for (int r = 0; r < 4; ++r) {
        long long row = m0 + wm * 64 + i * 16 + lq * 4 + r;
        if (row < M) atomicAdd(&out[row * 128 + col], oacc[i][j][r]);
      }
    }
}

extern "C" void kernel_launch(void* const* d_in, const int* in_sizes, int n_in,
                              void* d_out, int out_size, void* d_ws, size_t ws_size,
                              hipStream_t stream) {
  const float* z  = (const float*)d_in[0];
  const int*   ei = (const int*)d_in[1];
  const float* Wg = (const float*)d_in[2];
  const float* Ws = (const float*)d_in[3];
  const float* bg = (const float*)d_in[4];
  const float* W1 = (const float*)d_in[5];
  const float* b1 = (const float*)d_in[6];
  const float* W2 = (const float*)d_in[7];
  const float* b2 = (const float*)d_in[8];
  const float* W3 = (const float*)d_in[9];
  const float* b3 = (const float*)d_in[10];

  const int Nn = in_sizes[0] / 128;
  const int E  = in_sizes[1] / 2;
  const int* src = ei;
  const int* dst = ei + E;
  const int nb = (Nn + 1023) / 1024;
  const int gm128 = (Nn + 127) / 128;
  const long long Mpad = (long long)gm128 * 128;

  // workspace (sequential, no overlays; ~159 MB):
  char* base = (char*)d_ws;
  size_t off = 0;
  auto alloc = [&](size_t b) -> void* {
    void* p = base + off;
    off += (b + 255) & ~(size_t)255;
    return p;
  };
  f16* Xc        = (f16*)alloc((size_t)Mpad * 256 * 2);
  f16* h2        = (f16*)alloc((size_t)Mpad * 512 * 2);
  int* degi      = (int*)alloc((size_t)Nn * 4);
  int* row_start = (int*)alloc((size_t)(Nn + 1) * 4);
  int* cursor    = (int*)alloc((size_t)Nn * 4);
  int* adj       = (int*)alloc((size_t)E * 4);
  int* bsum      = (int*)alloc((size_t)nb * 4);
  int* boff      = (int*)alloc((size_t)nb * 4);
  f16* wgs       = (f16*)alloc((size_t)128 * 256 * 2);
  f16* wt1       = (f16*)alloc((size_t)512 * 128 * 2);
  f16* wt2       = (f16*)alloc((size_t)512 * 512 * 2);
  f16* wt3       = (f16*)alloc((size_t)128 * 512 * 2);

  // CSR build
  zero_kernel<<<(Nn + 255) / 256, 256, 0, stream>>>(degi, Nn);
  deg_count<<<(E + 255) / 256, 256, 0, stream>>>(dst, degi, E);
  scan_partial<<<nb, 256, 0, stream>>>(degi, bsum, Nn);
  scan_bsums<<<1, 64, 0, stream>>>(bsum, boff, row_start, nb, Nn);
  scan_final<<<nb, 256, 0, stream>>>(degi, boff, row_start, cursor, Nn);
  fill_adj<<<(E + 255) / 256, 256, 0, stream>>>(src, dst, cursor, adj, E);

  // weight prep + out pre-fill
  prep_weights<<<416, 256, 0, stream>>>(Wg, Ws, W1, W2, W3, wgs, wt1, wt2, wt3);
  fill_out<<<2048, 256, 0, stream>>>((float*)d_out, b3, out_size);

  // gather + Xcat (32 lanes per node)
  {
    long long tot = (long long)Nn * 32;
    gather_xcat<<<(int)((tot + 255) / 256), 256, 0, stream>>>(z, row_start, adj, Xc, Nn);
  }

  // fused MLP
  fused12<<<gm128, 256, 0, stream>>>(Xc, wgs, wt1, bg, b1, h2);
  fused34<<<dim3(gm128, 2), 512, 0, stream>>>(h2, wt2, wt3, b2, (float*)d_out, Nn);
}

// Round 11
// 337.689 us; speedup vs baseline: 1.5057x; 1.2277x over previous
//
#include <hip/hip_runtime.h>
#include <hip/hip_fp16.h>

// GDE func: out = MLP(relu(mean_agg(z,edges)@Wg + z@Ws + bg))
// Round 10 -> 11: revert to R5's proven GEMM structure (BM=128, BN=256,
// 8 waves of 64x64, 48KB LDS, drain schedule, 33% occupancy) with ONE
// isolated change: both-sides XOR swizzle (R5 had 1.9e7 bank-conflict
// cycles/dispatch = 28% of time; at 4 waves/SIMD the LDS pipe is shared,
// so conflicts are on the critical path -- unlike R6's 1-block/CU test).
// Second lever: gather reads a pre-cast f16 z-table (307 -> 154 MB).
// No fusion (R10's fused34 lost 74us), no atomics on out.

typedef _Float16 f16;
typedef __attribute__((ext_vector_type(4))) _Float16 f16x4;
typedef __attribute__((ext_vector_type(8))) _Float16 f16x8;
typedef __attribute__((ext_vector_type(4))) float f32x4;

__device__ __forceinline__ void async_load16(const void* g, void* lds) {
  __builtin_amdgcn_global_load_lds(
      (const __attribute__((address_space(1))) void*)g,
      (__attribute__((address_space(3))) void*)lds, 16, 0, 0);
}

__device__ __forceinline__ float fast_tanh(float x) {
  float a = fabsf(x);
  float e = __expf(-2.0f * a);
  float r = (1.0f - e) * __builtin_amdgcn_rcpf(1.0f + e);
  return copysignf(r, x);
}

__global__ __launch_bounds__(256) void zero_kernel(int* __restrict__ p, int n) {
  int i = blockIdx.x * 256 + threadIdx.x;
  int stride = gridDim.x * 256;
  for (; i < n; i += stride) p[i] = 0;
}

// ---- CSR build ----
__global__ __launch_bounds__(256) void deg_count(const int* __restrict__ dst,
                                                 int* __restrict__ degi, int E) {
  int e = blockIdx.x * 256 + threadIdx.x;
  if (e < E) atomicAdd(&degi[dst[e]], 1);
}

__global__ __launch_bounds__(256) void scan_partial(const int* __restrict__ degi,
                                                    int* __restrict__ bsum, int N) {
  __shared__ int lds[256];
  int b = blockIdx.x, t = threadIdx.x;
  int s = 0;
#pragma unroll
  for (int j = 0; j < 4; ++j) {
    int idx = b * 1024 + t * 4 + j;
    if (idx < N) s += degi[idx];
  }
  lds[t] = s;
  __syncthreads();
  for (int off = 128; off > 0; off >>= 1) {
    if (t < off) lds[t] += lds[t + off];
    __syncthreads();
  }
  if (t == 0) bsum[b] = lds[0];
}

__global__ void scan_bsums(const int* __restrict__ bsum, int* __restrict__ boff,
                           int* __restrict__ row_start, int nb, int N) {
  if (threadIdx.x == 0 && blockIdx.x == 0) {
    int acc = 0;
    for (int i = 0; i < nb; ++i) { boff[i] = acc; acc += bsum[i]; }
    row_start[N] = acc;  // == E
  }
}

__global__ __launch_bounds__(256) void scan_final(
    const int* __restrict__ degi, const int* __restrict__ boff,
    int* __restrict__ row_start, int* __restrict__ cursor, int N) {
  __shared__ int lds[256];
  int b = blockIdx.x, t = threadIdx.x;
  int base = b * 1024;
  int v[4];
  int s = 0;
#pragma unroll
  for (int j = 0; j < 4; ++j) {
    int idx = base + t * 4 + j;
    v[j] = (idx < N) ? degi[idx] : 0;
    s += v[j];
  }
  lds[t] = s;
  __syncthreads();
  for (int off = 1; off < 256; off <<= 1) {
    int x = lds[t];
    int y = (t >= off) ? lds[t - off] : 0;
    __syncthreads();
    lds[t] = x + y;
    __syncthreads();
  }
  int pre = boff[b] + lds[t] - s;
#pragma unroll
  for (int j = 0; j < 4; ++j) {
    int idx = base + t * 4 + j;
    if (idx < N) { row_start[idx] = pre; cursor[idx] = pre; pre += v[j]; }
  }
}

__global__ __launch_bounds__(256) void fill_adj(const int* __restrict__ src,
                                                const int* __restrict__ dst,
                                                int* __restrict__ cursor,
                                                int* __restrict__ adj, int E) {
  int e = blockIdx.x * 256 + threadIdx.x;
  if (e >= E) return;
  int p = atomicAdd(&cursor[dst[e]], 1);
  adj[p] = src[e];
}

// ---- cast z to f16 table (halves gather read traffic) ----
__global__ __launch_bounds__(256) void cast_z16(const float* __restrict__ z,
                                                f16* __restrict__ z16, int n4) {
  int i = blockIdx.x * 256 + threadIdx.x;
  int stride = gridDim.x * 256;
  for (; i < n4; i += stride) {
    float4 v = *(const float4*)(z + 4 * (long long)i);
    f16x4 c;
    c[0] = (f16)v.x; c[1] = (f16)v.y; c[2] = (f16)v.z; c[3] = (f16)v.w;
    *(f16x4*)(z16 + 4 * (long long)i) = c;
  }
}

// ---- fused gather + mean + Xcat from f16 table: 32 lanes/node ----
// lane covers 4 f16 cols (8B); row = 256B over 32 lanes; f32 accumulate.
__global__ __launch_bounds__(256) void gather_xcat(
    const f16* __restrict__ z16, const int* __restrict__ row_start,
    const int* __restrict__ adj, f16* __restrict__ Xc, int N) {
  int node = (blockIdx.x * 256 + threadIdx.x) >> 5;
  if (node >= N) return;
  int lane = threadIdx.x & 31;
  int beg = row_start[node], end = row_start[node + 1];
  float a0 = 0, a1 = 0, a2 = 0, a3 = 0;
  float b0 = 0, b1 = 0, b2 = 0, b3 = 0;
  float c0 = 0, c1 = 0, c2 = 0, c3 = 0;
  float d0 = 0, d1 = 0, d2 = 0, d3 = 0;
  int i = beg;
  for (; i + 4 <= end; i += 4) {
    int n0 = adj[i], n1 = adj[i + 1], n2 = adj[i + 2], n3 = adj[i + 3];
    f16x4 v0 = *(const f16x4*)(z16 + (long long)n0 * 128 + 4 * lane);
    f16x4 v1 = *(const f16x4*)(z16 + (long long)n1 * 128 + 4 * lane);
    f16x4 v2 = *(const f16x4*)(z16 + (long long)n2 * 128 + 4 * lane);
    f16x4 v3 = *(const f16x4*)(z16 + (long long)n3 * 128 + 4 * lane);
    a0 += (float)v0[0]; a1 += (float)v0[1]; a2 += (float)v0[2]; a3 += (float)v0[3];
    b0 += (float)v1[0]; b1 += (float)v1[1]; b2 += (float)v1[2]; b3 += (float)v1[3];
    c0 += (float)v2[0]; c1 += (float)v2[1]; c2 += (float)v2[2]; c3 += (float)v2[3];
    d0 += (float)v3[0]; d1 += (float)v3[1]; d2 += (float)v3[2]; d3 += (float)v3[3];
  }
  for (; i < end; ++i) {
    f16x4 v = *(const f16x4*)(z16 + (long long)adj[i] * 128 + 4 * lane);
    a0 += (float)v[0]; a1 += (float)v[1]; a2 += (float)v[2]; a3 += (float)v[3];
  }
  a0 += b0 + c0 + d0; a1 += b1 + c1 + d1;
  a2 += b2 + c2 + d2; a3 += b3 + c3 + d3;
  int dg = end - beg;
  float inv = 1.0f / (float)(dg > 1 ? dg : 1);
  long long o = (long long)node * 256;
  f16x4 m;
  m[0] = (f16)(a0 * inv); m[1] = (f16)(a1 * inv);
  m[2] = (f16)(a2 * inv); m[3] = (f16)(a3 * inv);
  *(f16x4*)(Xc + o + 4 * lane) = m;
  *(f16x4*)(Xc + o + 128 + 4 * lane) =
      *(const f16x4*)(z16 + (long long)node * 128 + 4 * lane);
}

// ---- merged weight prep: wgs[128c][256k], wt1[512c][128k], wt2[512c][512k],
// wt3[128c][512k], all f16 [col][K] ----
__global__ __launch_bounds__(256) void prep_weights(
    const float* __restrict__ Wg, const float* __restrict__ Ws,
    const float* __restrict__ W1, const float* __restrict__ W2,
    const float* __restrict__ W3, f16* __restrict__ wgs, f16* __restrict__ wt1,
    f16* __restrict__ wt2, f16* __restrict__ wt3) {
  int i = blockIdx.x * 256 + threadIdx.x;
  int stride = gridDim.x * 256;
  for (; i < 425984; i += stride) {
    if (i < 32768) {
      int n = i >> 8, k = i & 255;
      wgs[i] = (f16)((k < 128) ? Wg[k * 128 + n] : Ws[(k - 128) * 128 + n]);
    } else if (i < 98304) {
      int j = i - 32768, c = j >> 7, k = j & 127;
      wt1[j] = (f16)W1[k * 512 + c];
    } else if (i < 360448) {
      int j = i - 98304, c = j >> 9, k = j & 511;
      wt2[j] = (f16)W2[k * 512 + c];
    } else {
      int j = i - 360448, c = j >> 9, k = j & 511;
      wt3[j] = (f16)W3[k * 128 + c];
    }
  }
}

// --------- R5-geometry single-buffer drain MFMA GEMM + both-sides swizzle ----
// C[M,NOUT] = act(X[M,K] @ Wt^T + bias); Wt is [NOUT][K] f16, BK=64.
// Wave grid WM x WN, wave tile 64x64 (MI=NJ=4).
//   512-col layers: WM=2 WN=4 -> BM=128 BN=256, 512 thr, 48KB LDS (R5 config)
//   128-col layers: WM=2 WN=2 -> BM=128 BN=128, 256 thr, 32KB LDS
// Schedule per K-step: STAGE -> __syncthreads -> COMPUTE -> __syncthreads
// (R5-proven). Both-sides swizzle: source 16B-slot ^= row&7; read XORs same.
template <int K, int NOUT, int WM, int WN, int MI, int ACT, bool OUTF32>
__global__ __launch_bounds__(WM * WN * 64) void gemm_r(
    const f16* __restrict__ X, const f16* __restrict__ Wt,
    const float* __restrict__ bias, void* __restrict__ OutV, int M) {
  constexpr int NJ = 4;
  constexpr int BM = WM * MI * 16;
  constexpr int BN = WN * NJ * 16;
  constexpr int NTHR = WM * WN * 64;
  constexpr int CA = (BM * 128) / (NTHR * 16);
  constexpr int CB = (BN * 128) / (NTHR * 16);
  __shared__ __align__(16) f16 As[BM * 64];
  __shared__ __align__(16) f16 Bs[BN * 64];

  const int tid = threadIdx.x;
  const int wid = tid >> 6, lane = tid & 63;
  const int wm = wid / WN, wn = wid % WN;
  const int lr = lane & 15, lq = lane >> 4;
  const int rxor = lr & 7;
  const long long m0 = (long long)blockIdx.x * BM;
  const int n0 = blockIdx.y * BN;

  const f16* Ag = X + m0 * K;
  const f16* Bg = Wt + (long long)n0 * K;

  // hoisted per-thread stage source offsets (swizzled 16B slot)
  long long aOff[CA], bOff[CB];
#pragma unroll
  for (int c = 0; c < CA; ++c) {
    int f = c * NTHR + tid;
    int row = f >> 3, ss = (f & 7) ^ (row & 7);
    aOff[c] = (long long)row * K + ss * 8;
  }
#pragma unroll
  for (int c = 0; c < CB; ++c) {
    int f = c * NTHR + tid;
    int row = f >> 3, ss = (f & 7) ^ (row & 7);
    bOff[c] = (long long)row * K + ss * 8;
  }

  f32x4 acc[MI][NJ];
#pragma unroll
  for (int i = 0; i < MI; ++i)
#pragma unroll
    for (int j = 0; j < NJ; ++j)
#pragma unroll
      for (int r = 0; r < 4; ++r) acc[i][j][r] = 0.0f;

#pragma unroll 1
  for (int k0 = 0; k0 < K; k0 += 64) {
#pragma unroll
    for (int c = 0; c < CA; ++c)
      async_load16(Ag + aOff[c] + k0, (char*)As + c * NTHR * 16 + wid * 1024);
#pragma unroll
    for (int c = 0; c < CB; ++c)
      async_load16(Bg + bOff[c] + k0, (char*)Bs + c * NTHR * 16 + wid * 1024);
    __syncthreads();
#pragma unroll
    for (int kk = 0; kk < 64; kk += 32) {
      const int co = (((kk >> 3) + lq) ^ rxor) * 16;  // swizzled byte col
      f16x8 a[MI], b[NJ];
#pragma unroll
      for (int i = 0; i < MI; ++i)
        a[i] = *reinterpret_cast<const f16x8*>(
            (const char*)As + (wm * MI * 16 + i * 16 + lr) * 128 + co);
#pragma unroll
      for (int j = 0; j < NJ; ++j)
        b[j] = *reinterpret_cast<const f16x8*>(
            (const char*)Bs + (wn * NJ * 16 + j * 16 + lr) * 128 + co);
#pragma unroll
      for (int i = 0; i < MI; ++i)
#pragma unroll
        for (int j = 0; j < NJ; ++j)
          acc[i][j] = __builtin_amdgcn_mfma_f32_16x16x32_f16(a[i], b[j], acc[i][j], 0, 0, 0);
    }
    __syncthreads();
  }

#pragma unroll
  for (int i = 0; i < MI; ++i) {
#pragma unroll
    for (int j = 0; j < NJ; ++j) {
      int col = n0 + wn * NJ * 16 + j * 16 + lr;
      float bv = bias[col];
#pragma unroll
      for (int r = 0; r < 4; ++r) {
        long long row = m0 + wm * MI * 16 + i * 16 + lq * 4 + r;
        if (row < M) {
          float v = acc[i][j][r] + bv;
          if (ACT == 1) v = fmaxf(v, 0.0f);
          else if (ACT == 2) v = fast_tanh(v);
          if constexpr (OUTF32)
            ((float*)OutV)[row * NOUT + col] = v;
          else
            ((f16*)OutV)[row * NOUT + col] = (f16)v;
        }
      }
    }
  }
}

extern "C" void kernel_launch(void* const* d_in, const int* in_sizes, int n_in,
                              void* d_out, int out_size, void* d_ws, size_t ws_size,
                              hipStream_t stream) {
  const float* z  = (const float*)d_in[0];
  const int*   ei = (const int*)d_in[1];
  const float* Wg = (const float*)d_in[2];
  const float* Ws = (const float*)d_in[3];
  const float* bg = (const float*)d_in[4];
  const float* W1 = (const float*)d_in[5];
  const float* b1 = (const float*)d_in[6];
  const float* W2 = (const float*)d_in[7];
  const float* b2 = (const float*)d_in[8];
  const float* W3 = (const float*)d_in[9];
  const float* b3 = (const float*)d_in[10];

  const int Nn = in_sizes[0] / 128;
  const int E  = in_sizes[1] / 2;
  const int* src = ei;
  const int* dst = ei + E;
  const int nb = (Nn + 1023) / 1024;
  const int gm128 = (Nn + 127) / 128;
  const long long Mpad = (long long)gm128 * 128;

  // workspace overlay (peak ~207 MB):
  //   [0, 51.2M)        Xc    (gather -> gemm1)
  //   [51.2, 76.8M)     h1    (gemm1 -> gemm2)
  //   [76.8, ~106M)     CSR + z16 (build/cast -> gather; dead after gather)
  //   [0, 102.4M)       h3    (gemm3 -> gemm4; overlays Xc,h1,CSR head)
  //   [102.4, 204.8M)   h2    (gemm2 -> gemm3; overlays z16 tail - dead)
  //   [204.8M, ...)     prepped weights (~1.7 MB)
  char* base = (char*)d_ws;
  const size_t XCB = (size_t)Mpad * 256 * 2;
  const size_t H1B = (size_t)Mpad * 128 * 2;
  const size_t H3B = (size_t)Mpad * 512 * 2;
  f16* Xc = (f16*)(base);
  f16* h1 = (f16*)(base + XCB);
  f16* h3 = (f16*)(base);
  size_t off = XCB + H1B;
  auto alloc = [&](size_t b) -> void* {
    void* p = base + off;
    off += (b + 255) & ~(size_t)255;
    return p;
  };
  int* degi      = (int*)alloc((size_t)Nn * 4);
  int* row_start = (int*)alloc((size_t)(Nn + 1) * 4);
  int* cursor    = (int*)alloc((size_t)Nn * 4);
  int* adj       = (int*)alloc((size_t)E * 4);
  int* bsum      = (int*)alloc((size_t)nb * 4);
  int* boff      = (int*)alloc((size_t)nb * 4);
  f16* z16       = (f16*)alloc((size_t)Nn * 128 * 2);  // dead after gather
  off = H3B;  // h2 after h3 span
  f16* h2  = (f16*)alloc((size_t)Mpad * 512 * 2);
  f16* wgs = (f16*)alloc((size_t)128 * 256 * 2);
  f16* wt1 = (f16*)alloc((size_t)512 * 128 * 2);
  f16* wt2 = (f16*)alloc((size_t)512 * 512 * 2);
  f16* wt3 = (f16*)alloc((size_t)128 * 512 * 2);

  // CSR build
  zero_kernel<<<(Nn + 255) / 256, 256, 0, stream>>>(degi, Nn);
  deg_count<<<(E + 255) / 256, 256, 0, stream>>>(dst, degi, E);
  scan_partial<<<nb, 256, 0, stream>>>(degi, bsum, Nn);
  scan_bsums<<<1, 64, 0, stream>>>(bsum, boff, row_start, nb, Nn);
  scan_final<<<nb, 256, 0, stream>>>(degi, boff, row_start, cursor, Nn);
  fill_adj<<<(E + 255) / 256, 256, 0, stream>>>(src, dst, cursor, adj, E);

  // weight prep + z16 cast
  prep_weights<<<416, 256, 0, stream>>>(Wg, Ws, W1, W2, W3, wgs, wt1, wt2, wt3);
  cast_z16<<<2048, 256, 0, stream>>>(z, z16, Nn * 32);

  // gather + Xcat (32 lanes per node, f16 table)
  {
    long long tot = (long long)Nn * 32;
    gather_xcat<<<(int)((tot + 255) / 256), 256, 0, stream>>>(z16, row_start, adj, Xc, Nn);
  }

  // GEMMs: R5 geometry + swizzle.
  gemm_r<256, 128, 2, 2, 4, 1, false><<<dim3(gm128, 1), 256, 0, stream>>>(Xc, wgs, bg, (void*)h1, Nn);
  gemm_r<128, 512, 2, 4, 4, 2, false><<<dim3(gm128, 2), 512, 0, stream>>>(h1, wt1, b1, (void*)h2, Nn);
  gemm_r<512, 512, 2, 4, 4, 2, false><<<dim3(gm128, 2), 512, 0, stream>>>(h2, wt2, b2, (void*)h3, Nn);
  gemm_r<512, 128, 2, 2, 4, 0, true><<<dim3(gm128, 1), 256, 0, stream>>>(h3, wt3, b3, d_out, Nn);
}